// Round 4
// baseline (449.613 us; speedup 1.0000x reference)
//
#include <hip/hip_runtime.h>
#include <math.h>

#define NB  8
#define SEQ 2048
#define DIM 512

typedef short v8s __attribute__((ext_vector_type(8)));
typedef float v4f __attribute__((ext_vector_type(4)));

__device__ __forceinline__ unsigned short f2bf(float f) {
    unsigned int u = __float_as_uint(f);
    u += 0x7fffu + ((u >> 16) & 1u);
    return (unsigned short)(u >> 16);
}
__device__ __forceinline__ float bf2f(unsigned short h) {
    return __uint_as_float((unsigned int)h << 16);
}
// async 16B global->LDS; LDS dest = uniform base + lane*16
__device__ __forceinline__ void async16(const unsigned short* g, unsigned short* l) {
    __builtin_amdgcn_global_load_lds(
        (const __attribute__((address_space(1))) unsigned int*)g,
        (__attribute__((address_space(3))) unsigned int*)l, 16, 0, 0);
}
// wait LDS ops only: vmcnt(63) expcnt(7) lgkmcnt(0)
__device__ __forceinline__ void lds_fence() {
    __builtin_amdgcn_s_waitcnt(0xc07f);
    asm volatile("" ::: "memory");
}
__device__ __forceinline__ void flag_store(int* f, int v) {
    __hip_atomic_store(f, v, __ATOMIC_RELAXED, __HIP_MEMORY_SCOPE_WORKGROUP);
}
__device__ __forceinline__ void flag_wait(int* f, int v) {
    while (__hip_atomic_load(f, __ATOMIC_RELAXED, __HIP_MEMORY_SCOPE_WORKGROUP) < v) {}
    asm volatile("" ::: "memory");
}

// ---------------------------------------------------------------------------
// Fused q/v projection (z=0: q=query@Wq^T+bq -> qbf rowmajor;
//                       z=1: v=context@Wv^T+bv -> vT[b][e][n], side-writes cbf)
// 128x128 tile, BK=64, 256 threads. A staged from fp32 with in-stage bf16 cvt.
// ---------------------------------------------------------------------------
__global__ __launch_bounds__(256, 2)
void proj_qv(const float* __restrict__ query, const float* __restrict__ context,
             const float* __restrict__ Wq, const float* __restrict__ bq,
             const float* __restrict__ Wv, const float* __restrict__ bv,
             unsigned short* __restrict__ qbf, unsigned short* __restrict__ vT,
             unsigned short* __restrict__ cbf)
{
    __shared__ __align__(16) unsigned short As[128 * 64];
    __shared__ __align__(16) unsigned short Bs[128 * 64];

    const int z = blockIdx.z;
    const float* X    = z ? context : query;
    const float* W    = z ? Wv : Wq;
    const float* bias = z ? bv : bq;
    const bool   sidew = (z == 1) && (blockIdx.y == 0);

    const int t = threadIdx.x, wave = t >> 6, lane = t & 63;
    const int l15 = lane & 15, quad = lane >> 4;
    const int m0 = blockIdx.x * 128, e0 = blockIdx.y * 128;

    v4f hacc[2][8];
#pragma unroll
    for (int mt = 0; mt < 2; mt++)
#pragma unroll
        for (int nt = 0; nt < 8; nt++) hacc[mt][nt] = (v4f){0.f, 0.f, 0.f, 0.f};

#define STAGE_QV(bk)                                                           \
    _Pragma("unroll") for (int j = 0; j < 8; j++) {                            \
        int u = t * 8 + j;                                                     \
        int row = u >> 4, c4 = u & 15;                                         \
        int sc = (c4 >> 1) ^ (row & 7);                                        \
        float4 xv = *(const float4*)(X + (size_t)(m0 + row) * DIM + (bk) * 64 + c4 * 4); \
        ushort4 ox = make_ushort4(f2bf(xv.x), f2bf(xv.y), f2bf(xv.z), f2bf(xv.w)); \
        *(ushort4*)&As[row * 64 + sc * 8 + (c4 & 1) * 4] = ox;                 \
        if (sidew) *(ushort4*)&cbf[(size_t)(m0 + row) * DIM + (bk) * 64 + c4 * 4] = ox; \
        float4 wv = *(const float4*)(W + (size_t)(e0 + row) * DIM + (bk) * 64 + c4 * 4); \
        ushort4 ow = make_ushort4(f2bf(wv.x), f2bf(wv.y), f2bf(wv.z), f2bf(wv.w)); \
        *(ushort4*)&Bs[row * 64 + sc * 8 + (c4 & 1) * 4] = ow;                 \
    }

    STAGE_QV(0)
    for (int bk = 0; bk < 8; bk++) {
        __syncthreads();
#pragma unroll
        for (int kc = 0; kc < 2; kc++) {
            v8s a[2];
#pragma unroll
            for (int mt = 0; mt < 2; mt++) {
                int row = wave * 32 + mt * 16 + l15;
                a[mt] = *(const v8s*)&As[row * 64 + (((kc * 4 + quad) ^ (row & 7)) * 8)];
            }
#pragma unroll
            for (int nt = 0; nt < 8; nt++) {
                int er = nt * 16 + l15;
                v8s bfr = *(const v8s*)&Bs[er * 64 + (((kc * 4 + quad) ^ (er & 7)) * 8)];
#pragma unroll
                for (int mt = 0; mt < 2; mt++)
                    hacc[mt][nt] = __builtin_amdgcn_mfma_f32_16x16x32_bf16(a[mt], bfr, hacc[mt][nt], 0, 0, 0);
            }
        }
        __syncthreads();
        if (bk + 1 < 8) { STAGE_QV(bk + 1) }
    }
#undef STAGE_QV

#pragma unroll
    for (int mt = 0; mt < 2; mt++)
#pragma unroll
        for (int nt = 0; nt < 8; nt++) {
            int col = e0 + nt * 16 + l15;
            float bb = bias[col];
            if (z == 0) {
#pragma unroll
                for (int r = 0; r < 4; r++) {
                    int row = m0 + wave * 32 + mt * 16 + quad * 4 + r;
                    qbf[(size_t)row * DIM + col] = f2bf(hacc[mt][nt][r] + bb);
                }
            } else {
                int rowb = m0 + wave * 32 + mt * 16 + quad * 4;
                int bidx = rowb >> 11, n = rowb & 2047;
                ushort4 o = make_ushort4(f2bf(hacc[mt][nt][0] + bb), f2bf(hacc[mt][nt][1] + bb),
                                         f2bf(hacc[mt][nt][2] + bb), f2bf(hacc[mt][nt][3] + bb));
                *(ushort4*)&vT[(size_t)bidx * DIM * SEQ + (size_t)col * SEQ + n] = o;
            }
        }
}

// ---------------------------------------------------------------------------
// Flash v6: 512 thr (8 waves), 64 q-rows/block, K-tile 64, double-buffered Ks,
// 1 s_barrier/tile + LDS-flag syncs (no vmcnt drain mid-tile).
// Wave (strip=w&3, half=w>>2): S rows strip*16..+15 x keys half*32..+31;
// PV: wave owns d-cols wave*64..+63 for all 64 rows. Q/V/hacc in registers.
// ---------------------------------------------------------------------------
__global__ __launch_bounds__(512, 1)
void flash3(const unsigned short* __restrict__ qbf,
            const unsigned short* __restrict__ cbf,
            const unsigned short* __restrict__ vT,
            unsigned short* __restrict__ hhi,
            unsigned short* __restrict__ hlo)
{
    __shared__ __align__(16) unsigned short Ks[2][64 * 512];  // 128 KB, swizzled
    __shared__ __align__(16) unsigned short Ps[64 * 72];      // bf16 P
    __shared__ float Mpart[2][64];
    __shared__ float alphaS[64];
    __shared__ float LL[2][64];
    __shared__ int   flagM[8], flagP[8];

    const int t = threadIdx.x, wave = t >> 6, lane = t & 63;
    const int l15 = lane & 15, quad = lane >> 4;
    const int strip = wave & 3, half = wave >> 2;
    const int gid = blockIdx.x;
    const int b = gid & 7;                 // batch <-> XCD locality
    const int m0 = (gid >> 3) * 64;

    const unsigned short* ctxb = cbf + (size_t)b * SEQ * DIM;
    const unsigned short* vTb  = vT  + (size_t)b * DIM * SEQ;
    const float scale = 0.044194173824159216f;  // 1/sqrt(512)

    if (t < 8) { flagM[t] = 0; flagP[t] = 0; }

    // Q fragments (register-resident for the whole kernel)
    v8s qf[16];
    {
        const unsigned short* qrow = qbf + ((size_t)b * SEQ + m0 + strip * 16 + l15) * DIM;
#pragma unroll
        for (int kc = 0; kc < 16; kc++)
            qf[kc] = *(const v8s*)(qrow + kc * 32 + quad * 8);
    }
    v4f hacc[4][4];
#pragma unroll
    for (int m = 0; m < 4; m++)
#pragma unroll
        for (int dt = 0; dt < 4; dt++) hacc[m][dt] = (v4f){0.f, 0.f, 0.f, 0.f};
    float M[4], L[4];
#pragma unroll
    for (int r = 0; r < 4; r++) { M[r] = -INFINITY; L[r] = 0.f; }

    // stage K[0] -> buf 0
#pragma unroll
    for (int i = 0; i < 8; i++) {
        int row = wave * 8 + i;
        async16(ctxb + (size_t)row * DIM + (size_t)(lane ^ (row & 7)) * 8, &Ks[0][row * 512]);
    }

    for (int kt = 0; kt < SEQ / 64; kt++) {
        const int p = kt & 1;
        __syncthreads();   // drains K[kt] staging (in flight since last tile's top)
        // issue K[kt+1] -> other buffer (full tile to complete)
        if (kt + 1 < SEQ / 64) {
#pragma unroll
            for (int i = 0; i < 8; i++) {
                int row = wave * 8 + i;
                async16(ctxb + (size_t)((kt + 1) * 64 + row) * DIM + (size_t)(lane ^ (row & 7)) * 8,
                        &Ks[p ^ 1][row * 512]);
            }
        }
        // prefetch V fragments for this tile (register-resident)
        v8s vf[4][2];
#pragma unroll
        for (int dt = 0; dt < 4; dt++)
#pragma unroll
            for (int kc = 0; kc < 2; kc++)
                vf[dt][kc] = *(const v8s*)(vTb + (size_t)(wave * 64 + dt * 16 + l15) * SEQ
                                           + kt * 64 + kc * 32 + quad * 8);
        // ---- S = Q.K^T: 16 rows x 32 keys (4 accumulator chains) ----
        v4f sacc[2][2];
        sacc[0][0] = sacc[0][1] = sacc[1][0] = sacc[1][1] = (v4f){0.f, 0.f, 0.f, 0.f};
#pragma unroll
        for (int kc = 0; kc < 16; kc++) {
#pragma unroll
            for (int ct = 0; ct < 2; ct++) {
                int key = half * 32 + ct * 16 + l15;
                v8s kf = *(const v8s*)&Ks[p][key * 512 + (((kc * 4 + quad) ^ (key & 7)) * 8)];
                sacc[ct][kc & 1] = __builtin_amdgcn_mfma_f32_16x16x32_bf16(qf[kc], kf, sacc[ct][kc & 1], 0, 0, 0);
            }
        }
        float sc0[4], sc1[4], mx[4];
#pragma unroll
        for (int r = 0; r < 4; r++) {
            sc0[r] = (sacc[0][0][r] + sacc[0][1][r]) * scale;
            sc1[r] = (sacc[1][0][r] + sacc[1][1][r]) * scale;
            float m2 = fmaxf(sc0[r], sc1[r]);
#pragma unroll
            for (int off = 1; off < 16; off <<= 1)
                m2 = fmaxf(m2, __shfl_xor(m2, off, 64));
            mx[r] = m2;
            if (l15 == 0) Mpart[half][strip * 16 + quad * 4 + r] = m2;
        }
        lds_fence();
        if (lane == 0) flag_store(&flagM[wave], kt + 1);
        flag_wait(&flagM[wave ^ 4], kt + 1);
        // ---- softmax with combined max; publish P (bf16) + alpha ----
        float alr[4];
#pragma unroll
        for (int r = 0; r < 4; r++) {
            int row = strip * 16 + quad * 4 + r;
            float mo = Mpart[half ^ 1][row];
            float Mn = fmaxf(M[r], fmaxf(mx[r], mo));
            float al = __expf(M[r] - Mn);
            M[r] = Mn;
            alr[r] = al;
            float p0 = __expf(sc0[r] - Mn), p1 = __expf(sc1[r] - Mn);
            float rs = p0 + p1;
#pragma unroll
            for (int off = 1; off < 16; off <<= 1)
                rs += __shfl_xor(rs, off, 64);
            L[r] = L[r] * al + rs;
            Ps[row * 72 + half * 32 + l15]      = f2bf(p0);
            Ps[row * 72 + half * 32 + 16 + l15] = f2bf(p1);
            if (half == 0 && l15 == 0) alphaS[row] = al;
        }
        lds_fence();
        if (lane == 0) flag_store(&flagP[wave], kt + 1);
#pragma unroll
        for (int j = 0; j < 8; j++) flag_wait(&flagP[j], kt + 1);
        // ---- PV: rescale + h += P.V ----
#pragma unroll
        for (int m = 0; m < 4; m++) {
            v4f al4 = *(const v4f*)&alphaS[m * 16 + quad * 4];
#pragma unroll
            for (int dt = 0; dt < 4; dt++) hacc[m][dt] *= al4;
        }
#pragma unroll
        for (int kc = 0; kc < 2; kc++) {
            v8s pa[4];
#pragma unroll
            for (int m = 0; m < 4; m++)
                pa[m] = *(const v8s*)&Ps[(m * 16 + l15) * 72 + kc * 32 + quad * 8];
#pragma unroll
            for (int dt = 0; dt < 4; dt++)
#pragma unroll
                for (int m = 0; m < 4; m++)
                    hacc[m][dt] = __builtin_amdgcn_mfma_f32_16x16x32_bf16(pa[m], vf[dt][kc], hacc[m][dt], 0, 0, 0);
        }
    }

    // ---- epilogue: combine L halves, normalize, split hi/lo ----
    if (l15 == 0) {
#pragma unroll
        for (int r = 0; r < 4; r++) LL[half][strip * 16 + quad * 4 + r] = L[r];
    }
    __syncthreads();
#pragma unroll
    for (int m = 0; m < 4; m++) {
        v4f l0 = *(const v4f*)&LL[0][m * 16 + quad * 4];
        v4f l1 = *(const v4f*)&LL[1][m * 16 + quad * 4];
        v4f inv;
#pragma unroll
        for (int r = 0; r < 4; r++) inv[r] = 1.0f / (l0[r] + l1[r]);
#pragma unroll
        for (int dt = 0; dt < 4; dt++) {
            v4f o = hacc[m][dt] * inv;
#pragma unroll
            for (int r = 0; r < 4; r++) {
                size_t idx = ((size_t)b * SEQ + m0 + m * 16 + quad * 4 + r) * DIM
                             + wave * 64 + dt * 16 + l15;
                unsigned short hi = f2bf(o[r]);
                hhi[idx] = hi;
                hlo[idx] = f2bf(o[r] - bf2f(hi));
            }
        }
    }
}

// ---------------------------------------------------------------------------
// Split (hi/lo) o-projection: D ~= Ah*Bh + Al*Bh + Ah*Bl  (fp32-accurate)
// ---------------------------------------------------------------------------
__global__ __launch_bounds__(256, 2)
void proj_split(const unsigned short* __restrict__ Ahi, const unsigned short* __restrict__ Alo,
                const float* __restrict__ W, const float* __restrict__ bias,
                float* __restrict__ Y)
{
    __shared__ __align__(16) unsigned short Ah[128 * 64];
    __shared__ __align__(16) unsigned short Al[128 * 64];
    __shared__ __align__(16) unsigned short Bh[128 * 64];
    __shared__ __align__(16) unsigned short Bl[128 * 64];

    const int t = threadIdx.x, wave = t >> 6, lane = t & 63;
    const int l15 = lane & 15, quad = lane >> 4;
    const int m0 = blockIdx.x * 128, e0 = blockIdx.y * 128;

    v4f hacc[2][8];
#pragma unroll
    for (int mt = 0; mt < 2; mt++)
#pragma unroll
        for (int nt = 0; nt < 8; nt++) hacc[mt][nt] = (v4f){0.f, 0.f, 0.f, 0.f};

    const int lr8 = lane >> 3, lc8 = lane & 7;

#define STAGE_A2(bk)                                                           \
    _Pragma("unroll") for (int i = 0; i < 4; i++) {                            \
        int row = wave * 32 + i * 8 + lr8;                                     \
        int lc = lc8 ^ (row & 7);                                              \
        size_t ga = (size_t)(m0 + row) * DIM + (bk) * 64 + lc * 8;             \
        async16(Ahi + ga, &Ah[(wave * 32 + i * 8) * 64]);                      \
        async16(Alo + ga, &Al[(wave * 32 + i * 8) * 64]);                      \
    }
#define STAGE_B2(bk)                                                           \
    _Pragma("unroll") for (int j = 0; j < 8; j++) {                            \
        int u = t * 8 + j;                                                     \
        int row = u >> 4, c4 = u & 15;                                         \
        float4 wv = *(const float4*)(W + (size_t)(e0 + row) * DIM + (bk) * 64 + c4 * 4); \
        ushort4 oh = make_ushort4(f2bf(wv.x), f2bf(wv.y), f2bf(wv.z), f2bf(wv.w)); \
        ushort4 ol = make_ushort4(f2bf(wv.x - bf2f(oh.x)), f2bf(wv.y - bf2f(oh.y)), \
                                  f2bf(wv.z - bf2f(oh.z)), f2bf(wv.w - bf2f(oh.w))); \
        int sc = (c4 >> 1) ^ (row & 7);                                        \
        int sa = row * 64 + sc * 8 + (c4 & 1) * 4;                             \
        *(ushort4*)&Bh[sa] = oh;                                               \
        *(ushort4*)&Bl[sa] = ol;                                               \
    }

    STAGE_A2(0) STAGE_B2(0)
    for (int bk = 0; bk < 8; bk++) {
        __syncthreads();
#pragma unroll
        for (int kc = 0; kc < 2; kc++) {
            v8s ah[2], al[2];
#pragma unroll
            for (int mt = 0; mt < 2; mt++) {
                int row = wave * 32 + mt * 16 + l15;
                int sa = row * 64 + (((kc * 4 + quad) ^ (row & 7)) * 8);
                ah[mt] = *(const v8s*)&Ah[sa];
                al[mt] = *(const v8s*)&Al[sa];
            }
#pragma unroll
            for (int nt = 0; nt < 8; nt++) {
                int er = nt * 16 + l15;
                int sb = er * 64 + (((kc * 4 + quad) ^ (er & 7)) * 8);
                v8s bh = *(const v8s*)&Bh[sb];
                v8s bl = *(const v8s*)&Bl[sb];
#pragma unroll
                for (int mt = 0; mt < 2; mt++) {
                    hacc[mt][nt] = __builtin_amdgcn_mfma_f32_16x16x32_bf16(ah[mt], bh, hacc[mt][nt], 0, 0, 0);
                    hacc[mt][nt] = __builtin_amdgcn_mfma_f32_16x16x32_bf16(al[mt], bh, hacc[mt][nt], 0, 0, 0);
                    hacc[mt][nt] = __builtin_amdgcn_mfma_f32_16x16x32_bf16(ah[mt], bl, hacc[mt][nt], 0, 0, 0);
                }
            }
        }
        __syncthreads();
        if (bk + 1 < 8) { STAGE_A2(bk + 1) STAGE_B2(bk + 1) }
    }
#undef STAGE_A2
#undef STAGE_B2

#pragma unroll
    for (int mt = 0; mt < 2; mt++)
#pragma unroll
        for (int nt = 0; nt < 8; nt++) {
            int col = e0 + nt * 16 + l15;
            float bb = bias[col];
#pragma unroll
            for (int r = 0; r < 4; r++) {
                int row = m0 + wave * 32 + mt * 16 + quad * 4 + r;
                Y[(size_t)row * DIM + col] = hacc[mt][nt][r] + bb;
            }
        }
}

// ---------------------------------------------------------------------------
extern "C" void kernel_launch(void* const* d_in, const int* in_sizes, int n_in,
                              void* d_out, int out_size, void* d_ws, size_t ws_size,
                              hipStream_t stream)
{
    const float* query   = (const float*)d_in[0];
    const float* context = (const float*)d_in[1];
    const float* Wq      = (const float*)d_in[2];
    const float* bq      = (const float*)d_in[3];
    const float* Wv      = (const float*)d_in[4];
    const float* bv      = (const float*)d_in[5];
    const float* Wo      = (const float*)d_in[6];
    const float* bo      = (const float*)d_in[7];

    const size_t NE = (size_t)NB * SEQ * DIM;          // 8,388,608
    unsigned short* qbf = (unsigned short*)d_ws;       // 16.78 MB
    unsigned short* cbf = qbf + NE;                    // 16.78 MB
    unsigned short* hhi = cbf + NE;                    // 16.78 MB
    unsigned short* hlo = hhi + NE;                    // 16.78 MB (total 67.1 MB)
    unsigned short* vTb = (unsigned short*)d_out;      // v^T bf16 staged in d_out

    proj_qv   <<<dim3(128, 4, 2), 256, 0, stream>>>(query, context, Wq, bq, Wv, bv,
                                                    qbf, vTb, cbf);
    flash3    <<<256, 512, 0, stream>>>(qbf, cbf, vTb, hhi, hlo);
    proj_split<<<dim3(128, 4), 256, 0, stream>>>(hhi, hlo, Wo, bo, (float*)d_out);
}

// Round 5
// 393.971 us; speedup vs baseline: 1.1412x; 1.1412x over previous
//
#include <hip/hip_runtime.h>
#include <math.h>

#define NB  8
#define SEQ 2048
#define DIM 512

typedef short v8s __attribute__((ext_vector_type(8)));
typedef float v4f __attribute__((ext_vector_type(4)));

__device__ __forceinline__ unsigned short f2bf(float f) {
    unsigned int u = __float_as_uint(f);
    u += 0x7fffu + ((u >> 16) & 1u);
    return (unsigned short)(u >> 16);
}
__device__ __forceinline__ float bf2f(unsigned short h) {
    return __uint_as_float((unsigned int)h << 16);
}
// async 16B global->LDS; LDS dest = uniform base + lane*16
__device__ __forceinline__ void async16(const unsigned short* g, unsigned short* l) {
    __builtin_amdgcn_global_load_lds(
        (const __attribute__((address_space(1))) unsigned int*)g,
        (__attribute__((address_space(3))) unsigned int*)l, 16, 0, 0);
}
// wait LDS queue only: vmcnt(63) expcnt(7) lgkmcnt(0)
__device__ __forceinline__ void lds_fence() {
    __builtin_amdgcn_s_waitcnt(0xc07f);
    asm volatile("" ::: "memory");
}
// raw workgroup barrier WITHOUT vmcnt drain (K staging stays in flight)
__device__ __forceinline__ void bar() {
    __builtin_amdgcn_s_barrier();
    asm volatile("" ::: "memory");
}
__device__ __forceinline__ v8s cvt8(float4 a, float4 b) {
    v8s o;
    o[0] = (short)f2bf(a.x); o[1] = (short)f2bf(a.y);
    o[2] = (short)f2bf(a.z); o[3] = (short)f2bf(a.w);
    o[4] = (short)f2bf(b.x); o[5] = (short)f2bf(b.y);
    o[6] = (short)f2bf(b.z); o[7] = (short)f2bf(b.w);
    return o;
}

// ---------------------------------------------------------------------------
// prep: fp32->bf16 for query, context, Wq, Wv (one dispatch, 8 elems/thread)
// ---------------------------------------------------------------------------
__global__ __launch_bounds__(256)
void prep(const float* __restrict__ query, const float* __restrict__ context,
          const float* __restrict__ Wq, const float* __restrict__ Wv,
          unsigned short* __restrict__ qx, unsigned short* __restrict__ cbf,
          unsigned short* __restrict__ wqbf, unsigned short* __restrict__ wvbf)
{
    const int NE8 = NB * SEQ * DIM / 8;   // 1,048,576
    const int WE8 = DIM * DIM / 8;        // 32,768
    int i = blockIdx.x * 256 + threadIdx.x;
    const float* src; unsigned short* dst; int off;
    if (i < NE8)            { src = query;   dst = qx;   off = i; }
    else if (i < 2 * NE8)   { src = context; dst = cbf;  off = i - NE8; }
    else if (i < 2 * NE8 + WE8) { src = Wq;  dst = wqbf; off = i - 2 * NE8; }
    else                    { src = Wv;      dst = wvbf; off = i - 2 * NE8 - WE8; }
    float4 a = ((const float4*)src)[off * 2];
    float4 b = ((const float4*)src)[off * 2 + 1];
    *(v8s*)(dst + (size_t)off * 8) = cvt8(a, b);
}

// ---------------------------------------------------------------------------
// q/v projection, all-async16 staging (A and B both bf16 prepped).
// 128x128 tile, BK=64, 256 threads, 4 blocks/CU. z=0: q rowmajor; z=1: vT.
// ---------------------------------------------------------------------------
__global__ __launch_bounds__(256, 4)
void proj_qv2(const unsigned short* __restrict__ qx, const unsigned short* __restrict__ cbf,
              const unsigned short* __restrict__ wqbf, const unsigned short* __restrict__ wvbf,
              const float* __restrict__ bq, const float* __restrict__ bv,
              unsigned short* __restrict__ qbf, unsigned short* __restrict__ vT)
{
    __shared__ __align__(16) unsigned short As[128 * 64];
    __shared__ __align__(16) unsigned short Bs[128 * 64];

    const int z = blockIdx.z;
    const unsigned short* X = z ? cbf : qx;
    const unsigned short* W = z ? wvbf : wqbf;
    const float* bias = z ? bv : bq;

    const int t = threadIdx.x, wave = t >> 6, lane = t & 63;
    const int l15 = lane & 15, quad = lane >> 4;
    const int lr8 = lane >> 3, lc8 = lane & 7;
    const int m0 = blockIdx.x * 128, e0 = blockIdx.y * 128;

    v4f hacc[2][8];
#pragma unroll
    for (int mt = 0; mt < 2; mt++)
#pragma unroll
        for (int nt = 0; nt < 8; nt++) hacc[mt][nt] = (v4f){0.f, 0.f, 0.f, 0.f};

#define STAGE(bk)                                                              \
    _Pragma("unroll") for (int i = 0; i < 4; i++) {                            \
        int row = wave * 32 + i * 8 + lr8;                                     \
        int lc = lc8 ^ (row & 7);                                              \
        async16(X + (size_t)(m0 + row) * DIM + (bk) * 64 + lc * 8,             \
                &As[(wave * 32 + i * 8) * 64]);                                \
        async16(W + (size_t)(e0 + row) * DIM + (bk) * 64 + lc * 8,             \
                &Bs[(wave * 32 + i * 8) * 64]);                                \
    }

    STAGE(0)
    for (int bk = 0; bk < 8; bk++) {
        __syncthreads();
#pragma unroll
        for (int kc = 0; kc < 2; kc++) {
            v8s a[2];
#pragma unroll
            for (int mt = 0; mt < 2; mt++) {
                int row = wave * 32 + mt * 16 + l15;
                a[mt] = *(const v8s*)&As[row * 64 + (((kc * 4 + quad) ^ (row & 7)) * 8)];
            }
#pragma unroll
            for (int nt = 0; nt < 8; nt++) {
                int er = nt * 16 + l15;
                v8s bfr = *(const v8s*)&Bs[er * 64 + (((kc * 4 + quad) ^ (er & 7)) * 8)];
#pragma unroll
                for (int mt = 0; mt < 2; mt++)
                    hacc[mt][nt] = __builtin_amdgcn_mfma_f32_16x16x32_bf16(a[mt], bfr, hacc[mt][nt], 0, 0, 0);
            }
        }
        __syncthreads();
        if (bk + 1 < 8) { STAGE(bk + 1) }
    }
#undef STAGE

#pragma unroll
    for (int mt = 0; mt < 2; mt++)
#pragma unroll
        for (int nt = 0; nt < 8; nt++) {
            int col = e0 + nt * 16 + l15;
            float bb = bias[col];
            if (z == 0) {
#pragma unroll
                for (int r = 0; r < 4; r++) {
                    int row = m0 + wave * 32 + mt * 16 + quad * 4 + r;
                    qbf[(size_t)row * DIM + col] = f2bf(hacc[mt][nt][r] + bb);
                }
            } else {
                int rowb = m0 + wave * 32 + mt * 16 + quad * 4;
                int bidx = rowb >> 11, n = rowb & 2047;
                ushort4 o = make_ushort4(f2bf(hacc[mt][nt][0] + bb), f2bf(hacc[mt][nt][1] + bb),
                                         f2bf(hacc[mt][nt][2] + bb), f2bf(hacc[mt][nt][3] + bb));
                *(ushort4*)&vT[(size_t)bidx * DIM * SEQ + (size_t)col * SEQ + n] = o;
            }
        }
}

// ---------------------------------------------------------------------------
// Flash v6b: 512 thr (8 waves), 64 q-rows/block, double-buffered Ks,
// 1 __syncthreads/tile (drains K staging) + 2 raw s_barriers (no vmcnt drain).
// Wave (strip=w&3, half=w>>2): S rows strip*16 x keys half*32+32;
// PV: wave owns d-cols wave*64..+63. Q/V/hacc register-resident (512,1).
// ---------------------------------------------------------------------------
__global__ __launch_bounds__(512, 1)
void flash3b(const unsigned short* __restrict__ qbf,
             const unsigned short* __restrict__ cbf,
             const unsigned short* __restrict__ vT,
             unsigned short* __restrict__ hhi,
             unsigned short* __restrict__ hlo)
{
    __shared__ __align__(16) unsigned short Ks[2][64 * 512];  // 128 KB, swizzled
    __shared__ __align__(16) unsigned short Ps[64 * 72];      // bf16 P
    __shared__ float Mpart[2][64];
    __shared__ float alphaS[64];
    __shared__ float LL[2][64];

    const int t = threadIdx.x, wave = t >> 6, lane = t & 63;
    const int l15 = lane & 15, quad = lane >> 4;
    const int strip = wave & 3, half = wave >> 2;
    const int gid = blockIdx.x;
    const int b = gid & 7;                 // batch <-> XCD locality
    const int m0 = (gid >> 3) * 64;

    const unsigned short* ctxb = cbf + (size_t)b * SEQ * DIM;
    const unsigned short* vTb  = vT  + (size_t)b * DIM * SEQ;
    const float scale = 0.044194173824159216f;  // 1/sqrt(512)

    // Q fragments (register-resident for the whole kernel)
    v8s qf[16];
    {
        const unsigned short* qrow = qbf + ((size_t)b * SEQ + m0 + strip * 16 + l15) * DIM;
#pragma unroll
        for (int kc = 0; kc < 16; kc++)
            qf[kc] = *(const v8s*)(qrow + kc * 32 + quad * 8);
    }
    v4f hacc[4][4];
#pragma unroll
    for (int m = 0; m < 4; m++)
#pragma unroll
        for (int dt = 0; dt < 4; dt++) hacc[m][dt] = (v4f){0.f, 0.f, 0.f, 0.f};
    float M[4], L[4];
#pragma unroll
    for (int r = 0; r < 4; r++) { M[r] = -INFINITY; L[r] = 0.f; }

    // stage K[0] -> buf 0
#pragma unroll
    for (int i = 0; i < 8; i++) {
        int row = wave * 8 + i;
        async16(ctxb + (size_t)row * DIM + (size_t)(lane ^ (row & 7)) * 8, &Ks[0][row * 512]);
    }

    for (int kt = 0; kt < SEQ / 64; kt++) {
        const int p = kt & 1;
        __syncthreads();   // drains K[kt] staging (in flight since last tile)
        // issue K[kt+1] -> other buffer (a full tile of time to complete)
        if (kt + 1 < SEQ / 64) {
#pragma unroll
            for (int i = 0; i < 8; i++) {
                int row = wave * 8 + i;
                async16(ctxb + (size_t)((kt + 1) * 64 + row) * DIM + (size_t)(lane ^ (row & 7)) * 8,
                        &Ks[p ^ 1][row * 512]);
            }
        }
        // prefetch V fragments for this tile (register-resident)
        v8s vf[4][2];
#pragma unroll
        for (int dt = 0; dt < 4; dt++)
#pragma unroll
            for (int kc = 0; kc < 2; kc++)
                vf[dt][kc] = *(const v8s*)(vTb + (size_t)(wave * 64 + dt * 16 + l15) * SEQ
                                           + kt * 64 + kc * 32 + quad * 8);
        // ---- S = Q.K^T: 16 rows x 32 keys (4 accumulator chains) ----
        v4f sacc[2][2];
        sacc[0][0] = sacc[0][1] = sacc[1][0] = sacc[1][1] = (v4f){0.f, 0.f, 0.f, 0.f};
#pragma unroll
        for (int kc = 0; kc < 16; kc++) {
#pragma unroll
            for (int ct = 0; ct < 2; ct++) {
                int key = half * 32 + ct * 16 + l15;
                v8s kf = *(const v8s*)&Ks[p][key * 512 + (((kc * 4 + quad) ^ (key & 7)) * 8)];
                sacc[ct][kc & 1] = __builtin_amdgcn_mfma_f32_16x16x32_bf16(qf[kc], kf, sacc[ct][kc & 1], 0, 0, 0);
            }
        }
        float sc0[4], sc1[4], mx[4];
#pragma unroll
        for (int r = 0; r < 4; r++) {
            sc0[r] = (sacc[0][0][r] + sacc[0][1][r]) * scale;
            sc1[r] = (sacc[1][0][r] + sacc[1][1][r]) * scale;
            float m2 = fmaxf(sc0[r], sc1[r]);
#pragma unroll
            for (int off = 1; off < 16; off <<= 1)
                m2 = fmaxf(m2, __shfl_xor(m2, off, 64));
            mx[r] = m2;
            if (l15 == 0) Mpart[half][strip * 16 + quad * 4 + r] = m2;
        }
        lds_fence();
        bar();             // Mpart published (no vmcnt drain)
        // ---- softmax with combined max; publish P (bf16) + alpha ----
#pragma unroll
        for (int r = 0; r < 4; r++) {
            int row = strip * 16 + quad * 4 + r;
            float mo = Mpart[half ^ 1][row];
            float Mn = fmaxf(M[r], fmaxf(mx[r], mo));
            float al = __expf(M[r] - Mn);
            M[r] = Mn;
            float p0 = __expf(sc0[r] - Mn), p1 = __expf(sc1[r] - Mn);
            float rs = p0 + p1;
#pragma unroll
            for (int off = 1; off < 16; off <<= 1)
                rs += __shfl_xor(rs, off, 64);
            L[r] = L[r] * al + rs;
            Ps[row * 72 + half * 32 + l15]      = f2bf(p0);
            Ps[row * 72 + half * 32 + 16 + l15] = f2bf(p1);
            if (half == 0 && l15 == 0) alphaS[row] = al;
        }
        lds_fence();
        bar();             // Ps/alphaS published (no vmcnt drain)
        // ---- PV: rescale + h += P.V ----
#pragma unroll
        for (int m = 0; m < 4; m++) {
            v4f al4 = *(const v4f*)&alphaS[m * 16 + quad * 4];
#pragma unroll
            for (int dt = 0; dt < 4; dt++) hacc[m][dt] *= al4;
        }
#pragma unroll
        for (int kc = 0; kc < 2; kc++) {
            v8s pa[4];
#pragma unroll
            for (int m = 0; m < 4; m++)
                pa[m] = *(const v8s*)&Ps[(m * 16 + l15) * 72 + kc * 32 + quad * 8];
#pragma unroll
            for (int dt = 0; dt < 4; dt++)
#pragma unroll
                for (int m = 0; m < 4; m++)
                    hacc[m][dt] = __builtin_amdgcn_mfma_f32_16x16x32_bf16(pa[m], vf[dt][kc], hacc[m][dt], 0, 0, 0);
        }
    }

    // ---- epilogue: combine L halves, normalize, split hi/lo ----
    if (l15 == 0) {
#pragma unroll
        for (int r = 0; r < 4; r++) LL[half][strip * 16 + quad * 4 + r] = L[r];
    }
    __syncthreads();
#pragma unroll
    for (int m = 0; m < 4; m++) {
        v4f l0 = *(const v4f*)&LL[0][m * 16 + quad * 4];
        v4f l1 = *(const v4f*)&LL[1][m * 16 + quad * 4];
        v4f inv;
#pragma unroll
        for (int r = 0; r < 4; r++) inv[r] = 1.0f / (l0[r] + l1[r]);
#pragma unroll
        for (int dt = 0; dt < 4; dt++) {
            v4f o = hacc[m][dt] * inv;
#pragma unroll
            for (int r = 0; r < 4; r++) {
                size_t idx = ((size_t)b * SEQ + m0 + m * 16 + quad * 4 + r) * DIM
                             + wave * 64 + dt * 16 + l15;
                unsigned short hi = f2bf(o[r]);
                hhi[idx] = hi;
                hlo[idx] = f2bf(o[r] - bf2f(hi));
            }
        }
    }
}

// ---------------------------------------------------------------------------
// Split (hi/lo) o-projection: D ~= Ah*Bh + Al*Bh + Ah*Bl  (fp32-accurate)
// ---------------------------------------------------------------------------
__global__ __launch_bounds__(256, 2)
void proj_split(const unsigned short* __restrict__ Ahi, const unsigned short* __restrict__ Alo,
                const float* __restrict__ W, const float* __restrict__ bias,
                float* __restrict__ Y)
{
    __shared__ __align__(16) unsigned short Ah[128 * 64];
    __shared__ __align__(16) unsigned short Al[128 * 64];
    __shared__ __align__(16) unsigned short Bh[128 * 64];
    __shared__ __align__(16) unsigned short Bl[128 * 64];

    const int t = threadIdx.x, wave = t >> 6, lane = t & 63;
    const int l15 = lane & 15, quad = lane >> 4;
    const int m0 = blockIdx.x * 128, e0 = blockIdx.y * 128;

    v4f hacc[2][8];
#pragma unroll
    for (int mt = 0; mt < 2; mt++)
#pragma unroll
        for (int nt = 0; nt < 8; nt++) hacc[mt][nt] = (v4f){0.f, 0.f, 0.f, 0.f};

    const int lr8 = lane >> 3, lc8 = lane & 7;

#define STAGE_A2(bk)                                                           \
    _Pragma("unroll") for (int i = 0; i < 4; i++) {                            \
        int row = wave * 32 + i * 8 + lr8;                                     \
        int lc = lc8 ^ (row & 7);                                              \
        size_t ga = (size_t)(m0 + row) * DIM + (bk) * 64 + lc * 8;             \
        async16(Ahi + ga, &Ah[(wave * 32 + i * 8) * 64]);                      \
        async16(Alo + ga, &Al[(wave * 32 + i * 8) * 64]);                      \
    }
#define STAGE_B2(bk)                                                           \
    _Pragma("unroll") for (int j = 0; j < 8; j++) {                            \
        int u = t * 8 + j;                                                     \
        int row = u >> 4, c4 = u & 15;                                         \
        float4 wv = *(const float4*)(W + (size_t)(e0 + row) * DIM + (bk) * 64 + c4 * 4); \
        ushort4 oh = make_ushort4(f2bf(wv.x), f2bf(wv.y), f2bf(wv.z), f2bf(wv.w)); \
        ushort4 ol = make_ushort4(f2bf(wv.x - bf2f(oh.x)), f2bf(wv.y - bf2f(oh.y)), \
                                  f2bf(wv.z - bf2f(oh.z)), f2bf(wv.w - bf2f(oh.w))); \
        int sc = (c4 >> 1) ^ (row & 7);                                        \
        int sa = row * 64 + sc * 8 + (c4 & 1) * 4;                             \
        *(ushort4*)&Bh[sa] = oh;                                               \
        *(ushort4*)&Bl[sa] = ol;                                               \
    }

    STAGE_A2(0) STAGE_B2(0)
    for (int bk = 0; bk < 8; bk++) {
        __syncthreads();
#pragma unroll
        for (int kc = 0; kc < 2; kc++) {
            v8s ah[2], al[2];
#pragma unroll
            for (int mt = 0; mt < 2; mt++) {
                int row = wave * 32 + mt * 16 + l15;
                int sa = row * 64 + (((kc * 4 + quad) ^ (row & 7)) * 8);
                ah[mt] = *(const v8s*)&Ah[sa];
                al[mt] = *(const v8s*)&Al[sa];
            }
#pragma unroll
            for (int nt = 0; nt < 8; nt++) {
                int er = nt * 16 + l15;
                int sb = er * 64 + (((kc * 4 + quad) ^ (er & 7)) * 8);
                v8s bh = *(const v8s*)&Bh[sb];
                v8s bl = *(const v8s*)&Bl[sb];
#pragma unroll
                for (int mt = 0; mt < 2; mt++) {
                    hacc[mt][nt] = __builtin_amdgcn_mfma_f32_16x16x32_bf16(ah[mt], bh, hacc[mt][nt], 0, 0, 0);
                    hacc[mt][nt] = __builtin_amdgcn_mfma_f32_16x16x32_bf16(al[mt], bh, hacc[mt][nt], 0, 0, 0);
                    hacc[mt][nt] = __builtin_amdgcn_mfma_f32_16x16x32_bf16(ah[mt], bl, hacc[mt][nt], 0, 0, 0);
                }
            }
        }
        __syncthreads();
        if (bk + 1 < 8) { STAGE_A2(bk + 1) STAGE_B2(bk + 1) }
    }
#undef STAGE_A2
#undef STAGE_B2

#pragma unroll
    for (int mt = 0; mt < 2; mt++)
#pragma unroll
        for (int nt = 0; nt < 8; nt++) {
            int col = e0 + nt * 16 + l15;
            float bb = bias[col];
#pragma unroll
            for (int r = 0; r < 4; r++) {
                int row = m0 + wave * 32 + mt * 16 + quad * 4 + r;
                Y[(size_t)row * DIM + col] = hacc[mt][nt][r] + bb;
            }
        }
}

// ---------------------------------------------------------------------------
extern "C" void kernel_launch(void* const* d_in, const int* in_sizes, int n_in,
                              void* d_out, int out_size, void* d_ws, size_t ws_size,
                              hipStream_t stream)
{
    const float* query   = (const float*)d_in[0];
    const float* context = (const float*)d_in[1];
    const float* Wq      = (const float*)d_in[2];
    const float* bq      = (const float*)d_in[3];
    const float* Wv      = (const float*)d_in[4];
    const float* bv      = (const float*)d_in[5];
    const float* Wo      = (const float*)d_in[6];
    const float* bo      = (const float*)d_in[7];

    const size_t NE = (size_t)NB * SEQ * DIM;          // 8,388,608
    const size_t WE = (size_t)DIM * DIM;               // 262,144
    unsigned short* qbf = (unsigned short*)d_ws;       // 16.78 MB
    unsigned short* cbf = qbf + NE;                    // 16.78 MB
    unsigned short* hhi = cbf + NE;                    // 16.78 MB
    unsigned short* hlo = hhi + NE;                    // 16.78 MB (total 67.1 MB)
    unsigned short* vTb = (unsigned short*)d_out;      // v^T bf16 in d_out[0:NE] shorts
    unsigned short* qx  = ((unsigned short*)d_out) + NE; // query bf16 in d_out[NE:2NE]
    unsigned short* wqbf = hhi;                        // weights parked in hhi region
    unsigned short* wvbf = hhi + WE;                   // (dead before flash overwrites)

    prep      <<<8448, 256, 0, stream>>>(query, context, Wq, Wv, qx, cbf, wqbf, wvbf);
    proj_qv2  <<<dim3(128, 4, 2), 256, 0, stream>>>(qx, cbf, wqbf, wvbf, bq, bv, qbf, vTb);
    flash3b   <<<256, 512, 0, stream>>>(qbf, cbf, vTb, hhi, hlo);
    proj_split<<<dim3(128, 4), 256, 0, stream>>>(hhi, hlo, Wo, bo, (float*)d_out);
}